// Round 1
// 145.130 us; speedup vs baseline: 1.1380x; 1.1380x over previous
//
#include <hip/hip_runtime.h>

// LRF kernel, R7 (perf): same numerics as R6 (4 threads/batch, exact numpy
// einsum lane split, LAPACK-exact SVD). Change: svd3_vlast's bidiagonal-QR
// driver is fully specialized for n=3. The R6 version kept d[4]/e[3]/vt[4][4]/
// rc[2]/rs[2] as runtime-indexed arrays -> scratch memory (rule #20): every
// access in the serial QR chain was a ~200cy private-mem op (rocprof: 14MB
// excess WRITE_SIZE, VALUBusy 59% with 41% stall). Here mq/ll are enumerated
// (mq in {3,2}, ll in {1,2}, all i-loops = 2 trips), so all state lives in
// named scalars -> VGPRs. Every float op is transcribed 1:1 from R6 - bit
// identical results, no scratch.

#define DEVFN static __device__ __forceinline__

// ---------------- LAPACK fp32 helpers, gfortran-contract rounding ----------

DEVFN float slapy2f(float x, float y) {
#pragma clang fp contract(off)
  float xa = fabsf(x), ya = fabsf(y);
  float w = fmaxf(xa, ya);
  float z = fminf(xa, ya);
  if (z == 0.0f) return w;
  float q = z / w;
  return w * sqrtf(fmaf(q, q, 1.0f));
}

DEVFN float snrm2_2f(float a, float b) {
  double da = (double)a, db = (double)b;
  return (float)sqrt(da * da + db * db);
}

DEVFN void slartgf(float f, float g, float &cs, float &sn, float &r) {
#pragma clang fp contract(off)
  if (g == 0.0f) { cs = 1.0f; sn = 0.0f; r = f; return; }
  if (f == 0.0f) { cs = 0.0f; sn = copysignf(1.0f, g); r = fabsf(g); return; }
  float f1 = fabsf(f), g1 = fabsf(g);
  const float rtmin = 0x1p-63f;
  const float rtmax = 6.5219089e18f;
  if (f1 > rtmin && f1 < rtmax && g1 > rtmin && g1 < rtmax) {
    float d = sqrtf(fmaf(f, f, g * g));
    cs = f1 / d;
    r = copysignf(d, f);
    sn = g / r;
  } else {
    const float safmin = 0x1p-126f;
    const float safmax = 0x1p+126f;
    float u = fminf(safmax, fmaxf(safmin, fmaxf(f1, g1)));
    float fs = f / u, gs = g / u;
    float d = sqrtf(fmaf(fs, fs, gs * gs));
    cs = fabsf(fs) / d;
    r = copysignf(d, f);
    sn = gs / r;
    r = r * u;
  }
}

DEVFN void slas2f(float f, float g, float h, float &ssmin, float &ssmax) {
#pragma clang fp contract(off)
  float fa = fabsf(f), ga = fabsf(g), ha = fabsf(h);
  float fhmn = fminf(fa, ha), fhmx = fmaxf(fa, ha);
  if (fhmn == 0.0f) {
    ssmin = 0.0f;
    if (fhmx == 0.0f) {
      ssmax = ga;
    } else {
      float mx = fmaxf(fhmx, ga), mn = fminf(fhmx, ga);
      float q = mn / mx;
      ssmax = mx * sqrtf(fmaf(q, q, 1.0f));
    }
  } else {
    if (ga < fhmx) {
      float as = 1.0f + fhmn / fhmx;
      float at = (fhmx - fhmn) / fhmx;
      float qq = ga / fhmx;
      float au = qq * qq;
      float c = 2.0f / (sqrtf(fmaf(as, as, au)) + sqrtf(fmaf(at, at, au)));
      ssmin = fhmn * c;
      ssmax = fhmx / c;
    } else {
      float au = fhmx / ga;
      if (au == 0.0f) {
        ssmin = (fhmn * fhmx) / ga;
        ssmax = ga;
      } else {
        float as = 1.0f + fhmn / fhmx;
        float at = (fhmx - fhmn) / fhmx;
        float q1 = as * au, q2 = at * au;
        float c = 1.0f / (sqrtf(fmaf(q1, q1, 1.0f)) + sqrtf(fmaf(q2, q2, 1.0f)));
        ssmin = (fhmn * c) * au;
        ssmin = ssmin + ssmin;
        ssmax = ga / (c + c);
      }
    }
  }
}

DEVFN void slasv2f(float f, float g, float h, float &ssmin, float &ssmax,
                   float &snr, float &csr, float &snl, float &csl) {
#pragma clang fp contract(off)
  const float eps = 0x1p-24f;
  float ft = f, fa = fabsf(f), ht = h, ha = fabsf(h);
  int pmax = 1;
  bool swp = (ha > fa);
  if (swp) {
    pmax = 3;
    float tmp = ft; ft = ht; ht = tmp;
    tmp = fa; fa = ha; ha = tmp;
  }
  float gt = g, ga = fabsf(g);
  float clt = 0.0f, crt = 0.0f, slt = 0.0f, srt = 0.0f;
  if (ga == 0.0f) {
    ssmin = ha; ssmax = fa;
    clt = 1.0f; crt = 1.0f; slt = 0.0f; srt = 0.0f;
  } else {
    bool gasmal = true;
    if (ga > fa) {
      pmax = 2;
      if ((fa / ga) < eps) {
        gasmal = false;
        ssmax = ga;
        if (ha > 1.0f) ssmin = fa / (ga / ha);
        else ssmin = (fa / ga) * ha;
        clt = 1.0f; slt = ht / gt; srt = 1.0f; crt = ft / gt;
      }
    }
    if (gasmal) {
      float dd = fa - ha;
      float l;
      if (dd == fa) l = 1.0f;
      else l = dd / fa;
      float m = gt / ft;
      float t = 2.0f - l;
      float s = sqrtf(fmaf(m, m, t * t));
      float r;
      if (l == 0.0f) r = fabsf(m);
      else r = sqrtf(fmaf(m, m, l * l));
      float a = 0.5f * (s + r);
      ssmin = ha / a;
      ssmax = fa * a;
      float mm = m * m;
      if (mm == 0.0f) {
        if (l == 0.0f) t = copysignf(2.0f, ft) * copysignf(1.0f, gt);
        else t = gt / copysignf(dd, ft) + m / t;
      } else {
        t = (m / (s + t) + m / (r + l)) * (1.0f + a);
      }
      float l2 = sqrtf(fmaf(t, t, 4.0f));
      crt = 2.0f / l2;
      srt = t / l2;
      clt = fmaf(srt, m, crt) / a;
      slt = (ht / ft) * srt / a;
    }
  }
  if (swp) { csl = srt; snl = crt; csr = slt; snr = clt; }
  else { csl = clt; snl = slt; csr = crt; snr = srt; }
  float tsign = 0.0f;
  if (pmax == 1) tsign = copysignf(1.0f, csr) * copysignf(1.0f, csl) * copysignf(1.0f, f);
  if (pmax == 2) tsign = copysignf(1.0f, snr) * copysignf(1.0f, csl) * copysignf(1.0f, g);
  if (pmax == 3) tsign = copysignf(1.0f, snr) * copysignf(1.0f, snl) * copysignf(1.0f, h);
  ssmax = copysignf(ssmax, tsign);
  ssmin = copysignf(ssmin, tsign * copysignf(1.0f, f) * copysignf(1.0f, h));
}

// Givens row rotation as applied by sbdsqr's csrot loops:
//   tmp = vt[hi][col]; vt[hi][col] = ct*tmp - st*vt[lo][col];
//   vt[lo][col] = st*tmp + ct*vt[lo][col];
// guarded by (ct != 1 || st != 0) exactly as in R6.
#define GROT(hi1, hi2, hi3, lo1, lo2, lo3, ct_, st_)          \
  do {                                                        \
    float c__ = (ct_), s__ = (st_);                           \
    if (c__ != 1.0f || s__ != 0.0f) {                         \
      float t_;                                               \
      t_ = hi1; hi1 = fmaf(c__, t_, -(s__ * lo1)); lo1 = fmaf(s__, t_, c__ * lo1); \
      t_ = hi2; hi2 = fmaf(c__, t_, -(s__ * lo2)); lo2 = fmaf(s__, t_, c__ * lo2); \
      t_ = hi3; hi3 = fmaf(c__, t_, -(s__ * lo3)); lo3 = fmaf(s__, t_, c__ * lo3); \
    }                                                         \
  } while (0)

// slasv2 2x2 rotation applied to vt rows (lo = row mq-1, hi = row mq):
//   st = cosr*xx + sinr*yy; vt[hi] = cosr*yy - sinr*xx; vt[lo] = st;
#define ROT2X2(lo1, lo2, lo3, hi1, hi2, hi3, cr_, sr_)        \
  do {                                                        \
    float xx_, yy_, st_;                                      \
    xx_ = lo1; yy_ = hi1; st_ = fmaf(cr_, xx_, sr_ * yy_);    \
    hi1 = fmaf(cr_, yy_, -(sr_ * xx_)); lo1 = st_;            \
    xx_ = lo2; yy_ = hi2; st_ = fmaf(cr_, xx_, sr_ * yy_);    \
    hi2 = fmaf(cr_, yy_, -(sr_ * xx_)); lo2 = st_;            \
    xx_ = lo3; yy_ = hi3; st_ = fmaf(cr_, xx_, sr_ * yy_);    \
    hi3 = fmaf(cr_, yy_, -(sr_ * xx_)); lo3 = st_;            \
  } while (0)

#define VSWAP(a, b) { float t_ = (a); (a) = (b); (b) = t_; }

// sgesdd jobz='A' path for symmetric 3x3 -- arithmetic identical to R6,
// control flow specialized for n=3 so all state stays in VGPRs.
static __device__ void svd3_vlast(float c00, float c01, float c02,
                                  float c11, float c12, float c22,
                                  float vout[3]) {
#pragma clang fp contract(off)
  float a11 = c00, a12 = c01, a13 = c02;
  float a21 = c01, a22 = c11, a23 = c12;
  float a31 = c02, a32 = c12, a33 = c22;
  float d1, d2, d3, e1, e2;
  float taup1 = 0.0f, g2 = 0.0f;

  { // H(1)
    float xnorm = snrm2_2f(a21, a31);
    if (xnorm == 0.0f) {
      d1 = a11;
    } else {
      float beta = -copysignf(slapy2f(a11, xnorm), a11);
      float tauq1 = (beta - a11) / beta;
      float sc = 1.0f / (a11 - beta);
      float v2 = a21 * sc, v3 = a31 * sc;
      d1 = beta;
      float w2 = fmaf(a32, v3, a22 * v2);
      float w3 = fmaf(a33, v3, a23 * v2);
      w2 = w2 + a12;
      w3 = w3 + a13;
      a12 = fmaf(-tauq1, w2, a12);
      a13 = fmaf(-tauq1, w3, a13);
      float t2 = -tauq1 * w2;
      float t3 = -tauq1 * w3;
      a22 = fmaf(v2, t2, a22); a32 = fmaf(v3, t2, a32);
      a23 = fmaf(v2, t3, a23); a33 = fmaf(v3, t3, a33);
    }
  }
  { // G(1)
    float xnorm = fabsf(a13);
    if (xnorm == 0.0f) {
      e1 = a12;
    } else {
      float beta = -copysignf(slapy2f(a12, xnorm), a12);
      taup1 = (beta - a12) / beta;
      g2 = a13 * (1.0f / (a12 - beta));
      e1 = beta;
      float w2 = a23 * g2;
      float w3 = a33 * g2;
      w2 = w2 + a22;
      w3 = w3 + a32;
      a22 = fmaf(-taup1, w2, a22);
      a32 = fmaf(-taup1, w3, a32);
      float tg = -taup1 * g2;
      a23 = fmaf(w2, tg, a23);
      a33 = fmaf(w3, tg, a33);
    }
  }
  { // H(2)
    float xnorm = fabsf(a32);
    if (xnorm == 0.0f) {
      d2 = a22;
    } else {
      float beta = -copysignf(slapy2f(a22, xnorm), a22);
      float tauq2 = (beta - a22) / beta;
      float h3 = a32 * (1.0f / (a22 - beta));
      d2 = beta;
      float w = a33 * h3;
      w = w + a23;
      a23 = fmaf(-tauq2, w, a23);
      float tw = -tauq2 * w;
      a33 = fmaf(h3, tw, a33);
    }
  }
  e2 = a23;
  d3 = a33;

  // vt = identity, rows as scalars (row-major vtRC)
  float vt11 = 1.0f, vt12 = 0.0f, vt13 = 0.0f;
  float vt21 = 0.0f, vt22 = 1.0f, vt23 = 0.0f;
  float vt31 = 0.0f, vt32 = 0.0f, vt33 = 1.0f;

  const float eps = 0x1p-24f;
  const float unfl = 0x1p-126f;
  const float tol = 10.0f * eps;
  float thresh;
  {
    float sminoa = fabsf(d1);
    if (sminoa != 0.0f) {
      float mu = sminoa;
      // i = 2
      mu = fabsf(d2) * (mu / (mu + fabsf(e1)));
      sminoa = fminf(sminoa, mu);
      if (sminoa != 0.0f) {
        // i = 3
        mu = fabsf(d3) * (mu / (mu + fabsf(e2)));
        sminoa = fminf(sminoa, mu);
      }
    }
    sminoa = sminoa / sqrtf(3.0f);
    thresh = fmaxf(tol * sminoa, 6.0f * (3.0f * (3.0f * unfl)));
  }
  int mq = 3;
  int iterq = -1, iterdivn = 0;
  const int maxitdivn = 18;
  int oldll = -1, oldm = -1, idir = 0;
  float sminl = 0.0f;
  int guard = 0;

  while (true) {
    if (mq <= 1) break;
    if (++guard > 300) break;
    if (iterq >= 3) {
      iterq -= 3;
      iterdivn += 1;
      if (iterdivn >= maxitdivn) break;
    }
    if (mq == 2) {
      // scan: ll = 1; split iff |e1| <= thresh
      if (fabsf(e1) <= thresh) { e1 = 0.0f; mq = 1; continue; }
      // ll = 1 == mq-1: 2x2 on (d1, e1, d2), rotating vt rows 1,2
      float sigmn, sigmx, sinr, cosr, sinl, cosl;
      slasv2f(d1, e1, d2, sigmn, sigmx, sinr, cosr, sinl, cosl);
      d1 = sigmx; e1 = 0.0f; d2 = sigmn;
      ROT2X2(vt11, vt12, vt13, vt21, vt22, vt23, cosr, sinr);
      mq = 0;
      continue;
    }
    // ---- mq == 3 ----
    float smax = fabsf(d3);
    // scan lll=1 (ll=2): e2
    if (fabsf(e2) <= thresh) { e2 = 0.0f; mq = 2; continue; }
    smax = fmaxf(fmaxf(smax, fabsf(d2)), fabsf(e2));
    // scan lll=2 (ll=1): e1
    if (fabsf(e1) <= thresh) {
      e1 = 0.0f;
      // ll -> 2 == mq-1: 2x2 on (d2, e2, d3), rotating vt rows 2,3
      float sigmn, sigmx, sinr, cosr, sinl, cosl;
      slasv2f(d2, e2, d3, sigmn, sigmx, sinr, cosr, sinl, cosl);
      d2 = sigmx; e2 = 0.0f; d3 = sigmn;
      ROT2X2(vt21, vt22, vt23, vt31, vt32, vt33, cosr, sinr);
      mq = 1;
      continue;
    }
    smax = fmaxf(fmaxf(smax, fabsf(d1)), fabsf(e1));
    // ---- full sweep, ll = 1, mq = 3 ----
    if (1 > oldm || 3 < oldll)
      idir = (fabsf(d1) >= fabsf(d3)) ? 1 : 2;
    bool back = false;
    if (idir == 1) {
      if (fabsf(e2) <= tol * fabsf(d3)) { e2 = 0.0f; continue; }
      float mu = fabsf(d1);
      sminl = mu;
      // lll = 1
      if (fabsf(e1) <= tol * mu) { e1 = 0.0f; back = true; }
      else {
        mu = fabsf(d2) * (mu / (mu + fabsf(e1)));
        sminl = fminf(sminl, mu);
        // lll = 2
        if (fabsf(e2) <= tol * mu) { e2 = 0.0f; back = true; }
        else {
          mu = fabsf(d3) * (mu / (mu + fabsf(e2)));
          sminl = fminf(sminl, mu);
        }
      }
    } else {
      if (fabsf(e1) <= tol * fabsf(d1)) { e1 = 0.0f; continue; }
      float mu = fabsf(d3);
      sminl = mu;
      // lll = 2
      if (fabsf(e2) <= tol * mu) { e2 = 0.0f; back = true; }
      else {
        mu = fabsf(d2) * (mu / (mu + fabsf(e2)));
        sminl = fminf(sminl, mu);
        // lll = 1
        if (fabsf(e1) <= tol * mu) { e1 = 0.0f; back = true; }
        else {
          mu = fabsf(d1) * (mu / (mu + fabsf(e1)));
          sminl = fminf(sminl, mu);
        }
      }
    }
    if (back) continue;
    oldll = 1;
    oldm = 3;
    float shift = 0.0f;
    if (!((3.0f * tol) * (sminl / smax) <= fmaxf(eps, 0.01f * tol))) {
      float sll, rdum;
      if (idir == 1) { sll = fabsf(d1); slas2f(d2, e2, d3, shift, rdum); }
      else { sll = fabsf(d3); slas2f(d1, e1, d2, shift, rdum); }
      if (sll > 0.0f) {
        float q = shift / sll;
        if (q * q < eps) shift = 0.0f;
      }
    }
    iterq += 2;  // mq - ll
    float rc0, rc1, rs0, rs1;
    if (shift == 0.0f) {
      if (idir == 1) {
        float cs = 1.0f, oldcs = 1.0f, sn = 0.0f, oldsn = 0.0f, rr = 0.0f;
        // i = 1
        float fq = d1 * cs;
        slartgf(fq, e1, cs, sn, rr);
        float f2 = oldcs * rr;
        float g2q = d2 * sn;
        slartgf(f2, g2q, oldcs, oldsn, d1);
        rc0 = cs; rs0 = sn;
        // i = 2
        fq = d2 * cs;
        slartgf(fq, e2, cs, sn, rr);
        e1 = oldsn * rr;
        f2 = oldcs * rr;
        g2q = d3 * sn;
        slartgf(f2, g2q, oldcs, oldsn, d2);
        rc1 = cs; rs1 = sn;
        float h = d3 * cs;
        d3 = h * oldcs;
        e2 = h * oldsn;
        // apply ascending: j=0 rows(2,1), j=1 rows(3,2)
        GROT(vt21, vt22, vt23, vt11, vt12, vt13, rc0, rs0);
        GROT(vt31, vt32, vt33, vt21, vt22, vt23, rc1, rs1);
        if (fabsf(e2) <= thresh) e2 = 0.0f;
      } else {
        float cs = 1.0f, oldcs = 1.0f, sn = 0.0f, oldsn = 0.0f, rr = 0.0f;
        // i = 3
        float fq = d3 * cs;
        slartgf(fq, e2, cs, sn, rr);
        float f2 = oldcs * rr;
        float g2q = d2 * sn;
        slartgf(f2, g2q, oldcs, oldsn, d3);
        rc1 = oldcs; rs1 = -oldsn;
        // i = 2
        fq = d2 * cs;
        slartgf(fq, e1, cs, sn, rr);
        e2 = oldsn * rr;
        f2 = oldcs * rr;
        g2q = d1 * sn;
        slartgf(f2, g2q, oldcs, oldsn, d2);
        rc0 = oldcs; rs0 = -oldsn;
        float h = d1 * cs;
        d1 = h * oldcs;
        e1 = h * oldsn;
        // apply descending: j=1 rows(3,2), j=0 rows(2,1)
        GROT(vt31, vt32, vt33, vt21, vt22, vt23, rc1, rs1);
        GROT(vt21, vt22, vt23, vt11, vt12, vt13, rc0, rs0);
        if (fabsf(e1) <= thresh) e1 = 0.0f;
      }
    } else {
      if (idir == 1) {
        float fq = (fabsf(d1) - shift) * (copysignf(1.0f, d1) + shift / d1);
        float gq = e1;
        float cosr = 0, sinr = 0, cosl = 0, sinl = 0, rr = 0;
        // i = 1
        slartgf(fq, gq, cosr, sinr, rr);
        fq = fmaf(cosr, d1, sinr * e1);
        e1 = fmaf(cosr, e1, -(sinr * d1));
        gq = sinr * d2;
        d2 = cosr * d2;
        slartgf(fq, gq, cosl, sinl, rr);
        d1 = rr;
        fq = fmaf(cosl, e1, sinl * d2);
        d2 = fmaf(cosl, d2, -(sinl * e1));
        gq = sinl * e2;  // i < mq-1
        e2 = cosl * e2;
        rc0 = cosr; rs0 = sinr;
        // i = 2
        slartgf(fq, gq, cosr, sinr, rr);
        e1 = rr;
        fq = fmaf(cosr, d2, sinr * e2);
        e2 = fmaf(cosr, e2, -(sinr * d2));
        gq = sinr * d3;
        d3 = cosr * d3;
        slartgf(fq, gq, cosl, sinl, rr);
        d2 = rr;
        fq = fmaf(cosl, e2, sinl * d3);
        d3 = fmaf(cosl, d3, -(sinl * e2));
        rc1 = cosr; rs1 = sinr;
        e2 = fq;
        // apply ascending: j=0 rows(2,1), j=1 rows(3,2)
        GROT(vt21, vt22, vt23, vt11, vt12, vt13, rc0, rs0);
        GROT(vt31, vt32, vt33, vt21, vt22, vt23, rc1, rs1);
        if (fabsf(e2) <= thresh) e2 = 0.0f;
      } else {
        float fq = (fabsf(d3) - shift) * (copysignf(1.0f, d3) + shift / d3);
        float gq = e2;
        float cosr = 0, sinr = 0, cosl = 0, sinl = 0, rr = 0;
        // i = 3
        slartgf(fq, gq, cosr, sinr, rr);
        fq = fmaf(cosr, d3, sinr * e2);
        e2 = fmaf(cosr, e2, -(sinr * d3));
        gq = sinr * d2;
        d2 = cosr * d2;
        slartgf(fq, gq, cosl, sinl, rr);
        d3 = rr;
        fq = fmaf(cosl, e2, sinl * d2);
        d2 = fmaf(cosl, d2, -(sinl * e2));
        gq = sinl * e1;  // i > ll+1
        e1 = cosl * e1;
        rc1 = cosl; rs1 = -sinl;
        // i = 2
        slartgf(fq, gq, cosr, sinr, rr);
        e2 = rr;
        fq = fmaf(cosr, d2, sinr * e1);
        e1 = fmaf(cosr, e1, -(sinr * d2));
        gq = sinr * d1;
        d1 = cosr * d1;
        slartgf(fq, gq, cosl, sinl, rr);
        d2 = rr;
        fq = fmaf(cosl, e1, sinl * d1);
        d1 = fmaf(cosl, d1, -(sinl * e1));
        rc0 = cosl; rs0 = -sinl;
        e1 = fq;
        if (fabsf(e1) <= thresh) e1 = 0.0f;
        // apply descending: j=1 rows(3,2), j=0 rows(2,1)
        GROT(vt31, vt32, vt33, vt21, vt22, vt23, rc1, rs1);
        GROT(vt21, vt22, vt23, vt11, vt12, vt13, rc0, rs0);
      }
    }
  }
  // make singular values nonnegative (negate the corresponding vt row)
  if (d1 < 0.0f) { d1 = -d1; vt11 = -vt11; vt12 = -vt12; vt13 = -vt13; }
  if (d2 < 0.0f) { d2 = -d2; vt21 = -vt21; vt22 = -vt22; vt23 = -vt23; }
  if (d3 < 0.0f) { d3 = -d3; vt31 = -vt31; vt32 = -vt32; vt33 = -vt33; }
  // selection sort, descending (as sbdsqr: min of d[1..4-i] -> position 4-i)
  {
    int isub = 1; float smin = d1;
    if (d2 <= smin) { isub = 2; smin = d2; }
    if (d3 <= smin) { isub = 3; smin = d3; }
    if (isub != 3) {
      if (isub == 1) {
        d1 = d3; d3 = smin;
        VSWAP(vt11, vt31); VSWAP(vt12, vt32); VSWAP(vt13, vt33);
      } else {
        d2 = d3; d3 = smin;
        VSWAP(vt21, vt31); VSWAP(vt22, vt32); VSWAP(vt23, vt33);
      }
    }
  }
  {
    int isub = 1; float smin = d1;
    if (d2 <= smin) { isub = 2; smin = d2; }
    if (isub != 2) {
      d1 = d2; d2 = smin;
      VSWAP(vt11, vt21); VSWAP(vt12, vt22); VSWAP(vt13, vt23);
    }
  }
  float r1 = vt31, r2 = vt32, r3 = vt33;
  if (taup1 != 0.0f) {
    float w = r3 * g2;
    w = w + r2;
    r2 = fmaf(-taup1, w, r2);
    float tg = -taup1 * g2;
    r3 = fmaf(w, tg, r3);
  }
  vout[0] = r1;
  vout[1] = r2;
  vout[2] = r3;
}

// Quad hadd: (l0+l1)+(l2+l3), bit-identical in all 4 lanes of the quad
// (IEEE addition is commutative bitwise, so the xor pairing is exact).
DEVFN float qsum(float x) {
#pragma clang fp contract(off)
  float s = x + __shfl_xor(x, 1);
  return s + __shfl_xor(s, 2);
}
DEVFN int qsumi(int x) {
  int s = x + __shfl_xor(x, 1);
  return s + __shfl_xor(s, 2);
}

// One einsum vaccum-chain step for this lane's 4 elements of a 16-block,
// descending j (matches ab3->ab2->ab1->vaccum order). No FMA.
#define CHAIN4(acc, A, Bv)            \
  do {                                \
    float t_ = A[3] * Bv[3] + acc;    \
    t_ = A[2] * Bv[2] + t_;           \
    t_ = A[1] * Bv[1] + t_;           \
    acc = A[0] * Bv[0] + t_;          \
  } while (0)

// ---------------------------- main kernel ----------------------------------

__global__ __launch_bounds__(256, 4) void LRF_70695161692718_kernel(
    const float* __restrict__ xyz, const float* __restrict__ xyzg,
    const float* __restrict__ rl, float* __restrict__ out, int B) {
#pragma clang fp contract(off)
  int tid = blockIdx.x * blockDim.x + threadIdx.x;
  int b = tid >> 2;        // batch
  int l = tid & 3;         // einsum SIMD lane (column class c % 4 == l)
  if (b >= B) return;
  const float* Xg = xyzg + (size_t)b * 192;
  float cx = xyz[3 * b + 0], cy = xyz[3 * b + 1], cz = xyz[3 * b + 2];
  float r = rl[b];

  // Load this lane's 48 floats once into VGPRs: columns c = 4*i + l.
  float r0[16], r1[16], r2[16];
#pragma unroll
  for (int i = 0; i < 16; ++i) {
    int col = 4 * i + l;
    r0[i] = Xg[col];
    r1[i] = Xg[64 + col];
    r2[i] = Xg[128 + col];
  }

  // ---- pass 1: covariance (exact einsum chain per lane + quad hadd)
  float a00 = 0, a01 = 0, a02 = 0, a11 = 0, a12 = 0, a22 = 0;
#pragma unroll
  for (int Bk = 0; Bk < 4; ++Bk) {
    float x0[4], x1[4], x2[4];
#pragma unroll
    for (int j = 0; j < 4; ++j) {
      int i = 4 * Bk + j;
      x0[j] = cx - r0[i];
      x1[j] = cy - r1[i];
      x2[j] = cz - r2[i];
    }
    CHAIN4(a00, x0, x0);
    CHAIN4(a01, x0, x1);
    CHAIN4(a02, x0, x2);
    CHAIN4(a11, x1, x1);
    CHAIN4(a12, x1, x2);
    CHAIN4(a22, x2, x2);
  }
  a00 = qsum(a00) / 64.0f;
  a01 = qsum(a01) / 64.0f;
  a02 = qsum(a02) / 64.0f;
  a11 = qsum(a11) / 64.0f;
  a12 = qsum(a12) / 64.0f;
  a22 = qsum(a22) / 64.0f;

  float v[3];
  svd3_vlast(a00, a01, a02, a11, a12, a22, v);  // redundant across quad: free

  // ---- pass 2: center_proj counts (integer, order-free across quad)
  int npos = 0, nneg = 0;
#pragma unroll
  for (int i = 0; i < 16; ++i) {
    float x0 = cx - r0[i];
    float x1 = cy - r1[i];
    float x2 = cz - r2[i];
    float p = v[0] * x0;
    p = v[1] * x1 + p;
    p = v[2] * x2 + p;
    npos += (p > 0.001f) ? 1 : 0;
    nneg += (p < -0.001f) ? 1 : 0;
  }
  int sum_ = qsumi(npos) - qsumi(nneg);
  float sgn = (sum_ < 0) ? -1.0f : 1.0f;
  float zp0 = sgn * v[0], zp1 = sgn * v[1], zp2 = sgn * v[2];

  // ---- pass 3: vi_c (exact einsum chain per lane + quad hadd)
  float vx = 0, vy = 0, vz = 0;
#pragma unroll
  for (int Bk = 0; Bk < 4; ++Bk) {
    float w[4], q0[4], q1[4], q2[4];
#pragma unroll
    for (int j = 0; j < 4; ++j) {
      int i = 4 * Bk + j;
      float y0 = r0[i] - cx;
      float y1 = r1[i] - cy;
      float y2 = r2[i] - cz;
      float nm = zp0 * y0;
      nm = zp1 * y1 + nm;
      nm = zp2 * y2 + nm;
      q0[j] = y0 - zp0 * nm;
      q1[j] = y1 - zp1 * nm;
      q2[j] = y2 - zp2 * nm;
      float ss = y0 * y0;
      ss = ss + y1 * y1;
      ss = ss + y2 * y2;
      float xl2 = sqrtf(ss);
      float am = r - xl2;
      float alpha = am * am;
      float beta = nm * nm;
      w[j] = alpha * beta;
    }
    CHAIN4(vx, w, q0);
    CHAIN4(vy, w, q1);
    CHAIN4(vz, w, q2);
  }
  float vcx = qsum(vx);
  float vcy = qsum(vy);
  float vcz = qsum(vz);
  float ss = vcx * vcx;
  ss = ss + vcy * vcy;
  ss = ss + vcz * vcz;
  float den = sqrtf(ss) + 1e-10f;
  float xp0 = vcx / den, xp1 = vcy / den, xp2 = vcz / den;
  float yp0 = xp1 * zp2 - xp2 * zp1;
  float yp1 = xp2 * zp0 - xp0 * zp2;
  float yp2 = xp0 * zp1 - xp1 * zp0;

  // ---- pass 4: rotate and write this lane's 16 columns
  float* O = out + (size_t)b * 192;
#pragma unroll
  for (int i = 0; i < 16; ++i) {
    int col = 4 * i + l;
    float y0 = r0[i] - cx;
    float y1 = r1[i] - cy;
    float y2 = r2[i] - cz;
    float p0 = y0 / r, p1 = y1 / r, p2 = y2 / r;
    float t0 = xp0 * p0; t0 = xp1 * p1 + t0; t0 = xp2 * p2 + t0;
    float t1 = yp0 * p0; t1 = yp1 * p1 + t1; t1 = yp2 * p2 + t1;
    float t2 = zp0 * p0; t2 = zp1 * p1 + t2; t2 = zp2 * p2 + t2;
    O[col] = t0;
    O[64 + col] = t1;
    O[128 + col] = t2;
  }
}

extern "C" void kernel_launch(void* const* d_in, const int* in_sizes, int n_in,
                              void* d_out, int out_size, void* d_ws, size_t ws_size,
                              hipStream_t stream) {
  (void)n_in; (void)out_size; (void)d_ws; (void)ws_size;
  const float* xyz = (const float*)d_in[0];
  const float* xyzg = (const float*)d_in[1];
  const float* rl = (const float*)d_in[2];
  float* out = (float*)d_out;
  int B = in_sizes[2];  // r_lrf has one element per batch
  int threads = 256;
  int blocks = (B * 4 + threads - 1) / threads;
  LRF_70695161692718_kernel<<<blocks, threads, 0, stream>>>(xyz, xyzg, rl, out, B);
}

// Round 2
// 141.646 us; speedup vs baseline: 1.1660x; 1.0246x over previous
//
#include <hip/hip_runtime.h>

// LRF kernel, R8 (perf): identical numerics/structure to R7 (4 threads/batch,
// exact numpy einsum lane split, n=3-specialized LAPACK SVD, all-scalar state).
// Change: register-budget control. R7's __launch_bounds__(256,4) set only a
// MINIMUM of 4 waves/EU; the allocator chased 8 waves/EU (VGPR=64) and spilled
// the ~95-reg live set to scratch (rocprof: WRITE_SIZE 145MB vs 50MB output).
// The grid is 1024 blocks / 256 CUs = 4 waves/SIMD max, so 8-wave targeting
// buys nothing. amdgpu_waves_per_eu(2,4) pins the target at 4 waves/EU
// (128-VGPR budget) with relaxation to 2 waves instead of spilling.

#define DEVFN static __device__ __forceinline__

// ---------------- LAPACK fp32 helpers, gfortran-contract rounding ----------

DEVFN float slapy2f(float x, float y) {
#pragma clang fp contract(off)
  float xa = fabsf(x), ya = fabsf(y);
  float w = fmaxf(xa, ya);
  float z = fminf(xa, ya);
  if (z == 0.0f) return w;
  float q = z / w;
  return w * sqrtf(fmaf(q, q, 1.0f));
}

DEVFN float snrm2_2f(float a, float b) {
  double da = (double)a, db = (double)b;
  return (float)sqrt(da * da + db * db);
}

DEVFN void slartgf(float f, float g, float &cs, float &sn, float &r) {
#pragma clang fp contract(off)
  if (g == 0.0f) { cs = 1.0f; sn = 0.0f; r = f; return; }
  if (f == 0.0f) { cs = 0.0f; sn = copysignf(1.0f, g); r = fabsf(g); return; }
  float f1 = fabsf(f), g1 = fabsf(g);
  const float rtmin = 0x1p-63f;
  const float rtmax = 6.5219089e18f;
  if (f1 > rtmin && f1 < rtmax && g1 > rtmin && g1 < rtmax) {
    float d = sqrtf(fmaf(f, f, g * g));
    cs = f1 / d;
    r = copysignf(d, f);
    sn = g / r;
  } else {
    const float safmin = 0x1p-126f;
    const float safmax = 0x1p+126f;
    float u = fminf(safmax, fmaxf(safmin, fmaxf(f1, g1)));
    float fs = f / u, gs = g / u;
    float d = sqrtf(fmaf(fs, fs, gs * gs));
    cs = fabsf(fs) / d;
    r = copysignf(d, f);
    sn = gs / r;
    r = r * u;
  }
}

DEVFN void slas2f(float f, float g, float h, float &ssmin, float &ssmax) {
#pragma clang fp contract(off)
  float fa = fabsf(f), ga = fabsf(g), ha = fabsf(h);
  float fhmn = fminf(fa, ha), fhmx = fmaxf(fa, ha);
  if (fhmn == 0.0f) {
    ssmin = 0.0f;
    if (fhmx == 0.0f) {
      ssmax = ga;
    } else {
      float mx = fmaxf(fhmx, ga), mn = fminf(fhmx, ga);
      float q = mn / mx;
      ssmax = mx * sqrtf(fmaf(q, q, 1.0f));
    }
  } else {
    if (ga < fhmx) {
      float as = 1.0f + fhmn / fhmx;
      float at = (fhmx - fhmn) / fhmx;
      float qq = ga / fhmx;
      float au = qq * qq;
      float c = 2.0f / (sqrtf(fmaf(as, as, au)) + sqrtf(fmaf(at, at, au)));
      ssmin = fhmn * c;
      ssmax = fhmx / c;
    } else {
      float au = fhmx / ga;
      if (au == 0.0f) {
        ssmin = (fhmn * fhmx) / ga;
        ssmax = ga;
      } else {
        float as = 1.0f + fhmn / fhmx;
        float at = (fhmx - fhmn) / fhmx;
        float q1 = as * au, q2 = at * au;
        float c = 1.0f / (sqrtf(fmaf(q1, q1, 1.0f)) + sqrtf(fmaf(q2, q2, 1.0f)));
        ssmin = (fhmn * c) * au;
        ssmin = ssmin + ssmin;
        ssmax = ga / (c + c);
      }
    }
  }
}

DEVFN void slasv2f(float f, float g, float h, float &ssmin, float &ssmax,
                   float &snr, float &csr, float &snl, float &csl) {
#pragma clang fp contract(off)
  const float eps = 0x1p-24f;
  float ft = f, fa = fabsf(f), ht = h, ha = fabsf(h);
  int pmax = 1;
  bool swp = (ha > fa);
  if (swp) {
    pmax = 3;
    float tmp = ft; ft = ht; ht = tmp;
    tmp = fa; fa = ha; ha = tmp;
  }
  float gt = g, ga = fabsf(g);
  float clt = 0.0f, crt = 0.0f, slt = 0.0f, srt = 0.0f;
  if (ga == 0.0f) {
    ssmin = ha; ssmax = fa;
    clt = 1.0f; crt = 1.0f; slt = 0.0f; srt = 0.0f;
  } else {
    bool gasmal = true;
    if (ga > fa) {
      pmax = 2;
      if ((fa / ga) < eps) {
        gasmal = false;
        ssmax = ga;
        if (ha > 1.0f) ssmin = fa / (ga / ha);
        else ssmin = (fa / ga) * ha;
        clt = 1.0f; slt = ht / gt; srt = 1.0f; crt = ft / gt;
      }
    }
    if (gasmal) {
      float dd = fa - ha;
      float l;
      if (dd == fa) l = 1.0f;
      else l = dd / fa;
      float m = gt / ft;
      float t = 2.0f - l;
      float s = sqrtf(fmaf(m, m, t * t));
      float r;
      if (l == 0.0f) r = fabsf(m);
      else r = sqrtf(fmaf(m, m, l * l));
      float a = 0.5f * (s + r);
      ssmin = ha / a;
      ssmax = fa * a;
      float mm = m * m;
      if (mm == 0.0f) {
        if (l == 0.0f) t = copysignf(2.0f, ft) * copysignf(1.0f, gt);
        else t = gt / copysignf(dd, ft) + m / t;
      } else {
        t = (m / (s + t) + m / (r + l)) * (1.0f + a);
      }
      float l2 = sqrtf(fmaf(t, t, 4.0f));
      crt = 2.0f / l2;
      srt = t / l2;
      clt = fmaf(srt, m, crt) / a;
      slt = (ht / ft) * srt / a;
    }
  }
  if (swp) { csl = srt; snl = crt; csr = slt; snr = clt; }
  else { csl = clt; snl = slt; csr = crt; snr = srt; }
  float tsign = 0.0f;
  if (pmax == 1) tsign = copysignf(1.0f, csr) * copysignf(1.0f, csl) * copysignf(1.0f, f);
  if (pmax == 2) tsign = copysignf(1.0f, snr) * copysignf(1.0f, csl) * copysignf(1.0f, g);
  if (pmax == 3) tsign = copysignf(1.0f, snr) * copysignf(1.0f, snl) * copysignf(1.0f, h);
  ssmax = copysignf(ssmax, tsign);
  ssmin = copysignf(ssmin, tsign * copysignf(1.0f, f) * copysignf(1.0f, h));
}

// Givens row rotation as applied by sbdsqr's csrot loops:
//   tmp = vt[hi][col]; vt[hi][col] = ct*tmp - st*vt[lo][col];
//   vt[lo][col] = st*tmp + ct*vt[lo][col];
// guarded by (ct != 1 || st != 0) exactly as in R6.
#define GROT(hi1, hi2, hi3, lo1, lo2, lo3, ct_, st_)          \
  do {                                                        \
    float c__ = (ct_), s__ = (st_);                           \
    if (c__ != 1.0f || s__ != 0.0f) {                         \
      float t_;                                               \
      t_ = hi1; hi1 = fmaf(c__, t_, -(s__ * lo1)); lo1 = fmaf(s__, t_, c__ * lo1); \
      t_ = hi2; hi2 = fmaf(c__, t_, -(s__ * lo2)); lo2 = fmaf(s__, t_, c__ * lo2); \
      t_ = hi3; hi3 = fmaf(c__, t_, -(s__ * lo3)); lo3 = fmaf(s__, t_, c__ * lo3); \
    }                                                         \
  } while (0)

// slasv2 2x2 rotation applied to vt rows (lo = row mq-1, hi = row mq):
//   st = cosr*xx + sinr*yy; vt[hi] = cosr*yy - sinr*xx; vt[lo] = st;
#define ROT2X2(lo1, lo2, lo3, hi1, hi2, hi3, cr_, sr_)        \
  do {                                                        \
    float xx_, yy_, st_;                                      \
    xx_ = lo1; yy_ = hi1; st_ = fmaf(cr_, xx_, sr_ * yy_);    \
    hi1 = fmaf(cr_, yy_, -(sr_ * xx_)); lo1 = st_;            \
    xx_ = lo2; yy_ = hi2; st_ = fmaf(cr_, xx_, sr_ * yy_);    \
    hi2 = fmaf(cr_, yy_, -(sr_ * xx_)); lo2 = st_;            \
    xx_ = lo3; yy_ = hi3; st_ = fmaf(cr_, xx_, sr_ * yy_);    \
    hi3 = fmaf(cr_, yy_, -(sr_ * xx_)); lo3 = st_;            \
  } while (0)

#define VSWAP(a, b) { float t_ = (a); (a) = (b); (b) = t_; }

// sgesdd jobz='A' path for symmetric 3x3 -- arithmetic identical to R6,
// control flow specialized for n=3 so all state stays in VGPRs.
static __device__ void svd3_vlast(float c00, float c01, float c02,
                                  float c11, float c12, float c22,
                                  float vout[3]) {
#pragma clang fp contract(off)
  float a11 = c00, a12 = c01, a13 = c02;
  float a21 = c01, a22 = c11, a23 = c12;
  float a31 = c02, a32 = c12, a33 = c22;
  float d1, d2, d3, e1, e2;
  float taup1 = 0.0f, g2 = 0.0f;

  { // H(1)
    float xnorm = snrm2_2f(a21, a31);
    if (xnorm == 0.0f) {
      d1 = a11;
    } else {
      float beta = -copysignf(slapy2f(a11, xnorm), a11);
      float tauq1 = (beta - a11) / beta;
      float sc = 1.0f / (a11 - beta);
      float v2 = a21 * sc, v3 = a31 * sc;
      d1 = beta;
      float w2 = fmaf(a32, v3, a22 * v2);
      float w3 = fmaf(a33, v3, a23 * v2);
      w2 = w2 + a12;
      w3 = w3 + a13;
      a12 = fmaf(-tauq1, w2, a12);
      a13 = fmaf(-tauq1, w3, a13);
      float t2 = -tauq1 * w2;
      float t3 = -tauq1 * w3;
      a22 = fmaf(v2, t2, a22); a32 = fmaf(v3, t2, a32);
      a23 = fmaf(v2, t3, a23); a33 = fmaf(v3, t3, a33);
    }
  }
  { // G(1)
    float xnorm = fabsf(a13);
    if (xnorm == 0.0f) {
      e1 = a12;
    } else {
      float beta = -copysignf(slapy2f(a12, xnorm), a12);
      taup1 = (beta - a12) / beta;
      g2 = a13 * (1.0f / (a12 - beta));
      e1 = beta;
      float w2 = a23 * g2;
      float w3 = a33 * g2;
      w2 = w2 + a22;
      w3 = w3 + a32;
      a22 = fmaf(-taup1, w2, a22);
      a32 = fmaf(-taup1, w3, a32);
      float tg = -taup1 * g2;
      a23 = fmaf(w2, tg, a23);
      a33 = fmaf(w3, tg, a33);
    }
  }
  { // H(2)
    float xnorm = fabsf(a32);
    if (xnorm == 0.0f) {
      d2 = a22;
    } else {
      float beta = -copysignf(slapy2f(a22, xnorm), a22);
      float tauq2 = (beta - a22) / beta;
      float h3 = a32 * (1.0f / (a22 - beta));
      d2 = beta;
      float w = a33 * h3;
      w = w + a23;
      a23 = fmaf(-tauq2, w, a23);
      float tw = -tauq2 * w;
      a33 = fmaf(h3, tw, a33);
    }
  }
  e2 = a23;
  d3 = a33;

  // vt = identity, rows as scalars (row-major vtRC)
  float vt11 = 1.0f, vt12 = 0.0f, vt13 = 0.0f;
  float vt21 = 0.0f, vt22 = 1.0f, vt23 = 0.0f;
  float vt31 = 0.0f, vt32 = 0.0f, vt33 = 1.0f;

  const float eps = 0x1p-24f;
  const float unfl = 0x1p-126f;
  const float tol = 10.0f * eps;
  float thresh;
  {
    float sminoa = fabsf(d1);
    if (sminoa != 0.0f) {
      float mu = sminoa;
      // i = 2
      mu = fabsf(d2) * (mu / (mu + fabsf(e1)));
      sminoa = fminf(sminoa, mu);
      if (sminoa != 0.0f) {
        // i = 3
        mu = fabsf(d3) * (mu / (mu + fabsf(e2)));
        sminoa = fminf(sminoa, mu);
      }
    }
    sminoa = sminoa / sqrtf(3.0f);
    thresh = fmaxf(tol * sminoa, 6.0f * (3.0f * (3.0f * unfl)));
  }
  int mq = 3;
  int iterq = -1, iterdivn = 0;
  const int maxitdivn = 18;
  int oldll = -1, oldm = -1, idir = 0;
  float sminl = 0.0f;
  int guard = 0;

  while (true) {
    if (mq <= 1) break;
    if (++guard > 300) break;
    if (iterq >= 3) {
      iterq -= 3;
      iterdivn += 1;
      if (iterdivn >= maxitdivn) break;
    }
    if (mq == 2) {
      // scan: ll = 1; split iff |e1| <= thresh
      if (fabsf(e1) <= thresh) { e1 = 0.0f; mq = 1; continue; }
      // ll = 1 == mq-1: 2x2 on (d1, e1, d2), rotating vt rows 1,2
      float sigmn, sigmx, sinr, cosr, sinl, cosl;
      slasv2f(d1, e1, d2, sigmn, sigmx, sinr, cosr, sinl, cosl);
      d1 = sigmx; e1 = 0.0f; d2 = sigmn;
      ROT2X2(vt11, vt12, vt13, vt21, vt22, vt23, cosr, sinr);
      mq = 0;
      continue;
    }
    // ---- mq == 3 ----
    float smax = fabsf(d3);
    // scan lll=1 (ll=2): e2
    if (fabsf(e2) <= thresh) { e2 = 0.0f; mq = 2; continue; }
    smax = fmaxf(fmaxf(smax, fabsf(d2)), fabsf(e2));
    // scan lll=2 (ll=1): e1
    if (fabsf(e1) <= thresh) {
      e1 = 0.0f;
      // ll -> 2 == mq-1: 2x2 on (d2, e2, d3), rotating vt rows 2,3
      float sigmn, sigmx, sinr, cosr, sinl, cosl;
      slasv2f(d2, e2, d3, sigmn, sigmx, sinr, cosr, sinl, cosl);
      d2 = sigmx; e2 = 0.0f; d3 = sigmn;
      ROT2X2(vt21, vt22, vt23, vt31, vt32, vt33, cosr, sinr);
      mq = 1;
      continue;
    }
    smax = fmaxf(fmaxf(smax, fabsf(d1)), fabsf(e1));
    // ---- full sweep, ll = 1, mq = 3 ----
    if (1 > oldm || 3 < oldll)
      idir = (fabsf(d1) >= fabsf(d3)) ? 1 : 2;
    bool back = false;
    if (idir == 1) {
      if (fabsf(e2) <= tol * fabsf(d3)) { e2 = 0.0f; continue; }
      float mu = fabsf(d1);
      sminl = mu;
      // lll = 1
      if (fabsf(e1) <= tol * mu) { e1 = 0.0f; back = true; }
      else {
        mu = fabsf(d2) * (mu / (mu + fabsf(e1)));
        sminl = fminf(sminl, mu);
        // lll = 2
        if (fabsf(e2) <= tol * mu) { e2 = 0.0f; back = true; }
        else {
          mu = fabsf(d3) * (mu / (mu + fabsf(e2)));
          sminl = fminf(sminl, mu);
        }
      }
    } else {
      if (fabsf(e1) <= tol * fabsf(d1)) { e1 = 0.0f; continue; }
      float mu = fabsf(d3);
      sminl = mu;
      // lll = 2
      if (fabsf(e2) <= tol * mu) { e2 = 0.0f; back = true; }
      else {
        mu = fabsf(d2) * (mu / (mu + fabsf(e2)));
        sminl = fminf(sminl, mu);
        // lll = 1
        if (fabsf(e1) <= tol * mu) { e1 = 0.0f; back = true; }
        else {
          mu = fabsf(d1) * (mu / (mu + fabsf(e1)));
          sminl = fminf(sminl, mu);
        }
      }
    }
    if (back) continue;
    oldll = 1;
    oldm = 3;
    float shift = 0.0f;
    if (!((3.0f * tol) * (sminl / smax) <= fmaxf(eps, 0.01f * tol))) {
      float sll, rdum;
      if (idir == 1) { sll = fabsf(d1); slas2f(d2, e2, d3, shift, rdum); }
      else { sll = fabsf(d3); slas2f(d1, e1, d2, shift, rdum); }
      if (sll > 0.0f) {
        float q = shift / sll;
        if (q * q < eps) shift = 0.0f;
      }
    }
    iterq += 2;  // mq - ll
    float rc0, rc1, rs0, rs1;
    if (shift == 0.0f) {
      if (idir == 1) {
        float cs = 1.0f, oldcs = 1.0f, sn = 0.0f, oldsn = 0.0f, rr = 0.0f;
        // i = 1
        float fq = d1 * cs;
        slartgf(fq, e1, cs, sn, rr);
        float f2 = oldcs * rr;
        float g2q = d2 * sn;
        slartgf(f2, g2q, oldcs, oldsn, d1);
        rc0 = cs; rs0 = sn;
        // i = 2
        fq = d2 * cs;
        slartgf(fq, e2, cs, sn, rr);
        e1 = oldsn * rr;
        f2 = oldcs * rr;
        g2q = d3 * sn;
        slartgf(f2, g2q, oldcs, oldsn, d2);
        rc1 = cs; rs1 = sn;
        float h = d3 * cs;
        d3 = h * oldcs;
        e2 = h * oldsn;
        // apply ascending: j=0 rows(2,1), j=1 rows(3,2)
        GROT(vt21, vt22, vt23, vt11, vt12, vt13, rc0, rs0);
        GROT(vt31, vt32, vt33, vt21, vt22, vt23, rc1, rs1);
        if (fabsf(e2) <= thresh) e2 = 0.0f;
      } else {
        float cs = 1.0f, oldcs = 1.0f, sn = 0.0f, oldsn = 0.0f, rr = 0.0f;
        // i = 3
        float fq = d3 * cs;
        slartgf(fq, e2, cs, sn, rr);
        float f2 = oldcs * rr;
        float g2q = d2 * sn;
        slartgf(f2, g2q, oldcs, oldsn, d3);
        rc1 = oldcs; rs1 = -oldsn;
        // i = 2
        fq = d2 * cs;
        slartgf(fq, e1, cs, sn, rr);
        e2 = oldsn * rr;
        f2 = oldcs * rr;
        g2q = d1 * sn;
        slartgf(f2, g2q, oldcs, oldsn, d2);
        rc0 = oldcs; rs0 = -oldsn;
        float h = d1 * cs;
        d1 = h * oldcs;
        e1 = h * oldsn;
        // apply descending: j=1 rows(3,2), j=0 rows(2,1)
        GROT(vt31, vt32, vt33, vt21, vt22, vt23, rc1, rs1);
        GROT(vt21, vt22, vt23, vt11, vt12, vt13, rc0, rs0);
        if (fabsf(e1) <= thresh) e1 = 0.0f;
      }
    } else {
      if (idir == 1) {
        float fq = (fabsf(d1) - shift) * (copysignf(1.0f, d1) + shift / d1);
        float gq = e1;
        float cosr = 0, sinr = 0, cosl = 0, sinl = 0, rr = 0;
        // i = 1
        slartgf(fq, gq, cosr, sinr, rr);
        fq = fmaf(cosr, d1, sinr * e1);
        e1 = fmaf(cosr, e1, -(sinr * d1));
        gq = sinr * d2;
        d2 = cosr * d2;
        slartgf(fq, gq, cosl, sinl, rr);
        d1 = rr;
        fq = fmaf(cosl, e1, sinl * d2);
        d2 = fmaf(cosl, d2, -(sinl * e1));
        gq = sinl * e2;  // i < mq-1
        e2 = cosl * e2;
        rc0 = cosr; rs0 = sinr;
        // i = 2
        slartgf(fq, gq, cosr, sinr, rr);
        e1 = rr;
        fq = fmaf(cosr, d2, sinr * e2);
        e2 = fmaf(cosr, e2, -(sinr * d2));
        gq = sinr * d3;
        d3 = cosr * d3;
        slartgf(fq, gq, cosl, sinl, rr);
        d2 = rr;
        fq = fmaf(cosl, e2, sinl * d3);
        d3 = fmaf(cosl, d3, -(sinl * e2));
        rc1 = cosr; rs1 = sinr;
        e2 = fq;
        // apply ascending: j=0 rows(2,1), j=1 rows(3,2)
        GROT(vt21, vt22, vt23, vt11, vt12, vt13, rc0, rs0);
        GROT(vt31, vt32, vt33, vt21, vt22, vt23, rc1, rs1);
        if (fabsf(e2) <= thresh) e2 = 0.0f;
      } else {
        float fq = (fabsf(d3) - shift) * (copysignf(1.0f, d3) + shift / d3);
        float gq = e2;
        float cosr = 0, sinr = 0, cosl = 0, sinl = 0, rr = 0;
        // i = 3
        slartgf(fq, gq, cosr, sinr, rr);
        fq = fmaf(cosr, d3, sinr * e2);
        e2 = fmaf(cosr, e2, -(sinr * d3));
        gq = sinr * d2;
        d2 = cosr * d2;
        slartgf(fq, gq, cosl, sinl, rr);
        d3 = rr;
        fq = fmaf(cosl, e2, sinl * d2);
        d2 = fmaf(cosl, d2, -(sinl * e2));
        gq = sinl * e1;  // i > ll+1
        e1 = cosl * e1;
        rc1 = cosl; rs1 = -sinl;
        // i = 2
        slartgf(fq, gq, cosr, sinr, rr);
        e2 = rr;
        fq = fmaf(cosr, d2, sinr * e1);
        e1 = fmaf(cosr, e1, -(sinr * d2));
        gq = sinr * d1;
        d1 = cosr * d1;
        slartgf(fq, gq, cosl, sinl, rr);
        d2 = rr;
        fq = fmaf(cosl, e1, sinl * d1);
        d1 = fmaf(cosl, d1, -(sinl * e1));
        rc0 = cosl; rs0 = -sinl;
        e1 = fq;
        if (fabsf(e1) <= thresh) e1 = 0.0f;
        // apply descending: j=1 rows(3,2), j=0 rows(2,1)
        GROT(vt31, vt32, vt33, vt21, vt22, vt23, rc1, rs1);
        GROT(vt21, vt22, vt23, vt11, vt12, vt13, rc0, rs0);
      }
    }
  }
  // make singular values nonnegative (negate the corresponding vt row)
  if (d1 < 0.0f) { d1 = -d1; vt11 = -vt11; vt12 = -vt12; vt13 = -vt13; }
  if (d2 < 0.0f) { d2 = -d2; vt21 = -vt21; vt22 = -vt22; vt23 = -vt23; }
  if (d3 < 0.0f) { d3 = -d3; vt31 = -vt31; vt32 = -vt32; vt33 = -vt33; }
  // selection sort, descending (as sbdsqr: min of d[1..4-i] -> position 4-i)
  {
    int isub = 1; float smin = d1;
    if (d2 <= smin) { isub = 2; smin = d2; }
    if (d3 <= smin) { isub = 3; smin = d3; }
    if (isub != 3) {
      if (isub == 1) {
        d1 = d3; d3 = smin;
        VSWAP(vt11, vt31); VSWAP(vt12, vt32); VSWAP(vt13, vt33);
      } else {
        d2 = d3; d3 = smin;
        VSWAP(vt21, vt31); VSWAP(vt22, vt32); VSWAP(vt23, vt33);
      }
    }
  }
  {
    int isub = 1; float smin = d1;
    if (d2 <= smin) { isub = 2; smin = d2; }
    if (isub != 2) {
      d1 = d2; d2 = smin;
      VSWAP(vt11, vt21); VSWAP(vt12, vt22); VSWAP(vt13, vt23);
    }
  }
  float r1 = vt31, r2 = vt32, r3 = vt33;
  if (taup1 != 0.0f) {
    float w = r3 * g2;
    w = w + r2;
    r2 = fmaf(-taup1, w, r2);
    float tg = -taup1 * g2;
    r3 = fmaf(w, tg, r3);
  }
  vout[0] = r1;
  vout[1] = r2;
  vout[2] = r3;
}

// Quad hadd: (l0+l1)+(l2+l3), bit-identical in all 4 lanes of the quad
// (IEEE addition is commutative bitwise, so the xor pairing is exact).
DEVFN float qsum(float x) {
#pragma clang fp contract(off)
  float s = x + __shfl_xor(x, 1);
  return s + __shfl_xor(s, 2);
}
DEVFN int qsumi(int x) {
  int s = x + __shfl_xor(x, 1);
  return s + __shfl_xor(s, 2);
}

// One einsum vaccum-chain step for this lane's 4 elements of a 16-block,
// descending j (matches ab3->ab2->ab1->vaccum order). No FMA.
#define CHAIN4(acc, A, Bv)            \
  do {                                \
    float t_ = A[3] * Bv[3] + acc;    \
    t_ = A[2] * Bv[2] + t_;           \
    t_ = A[1] * Bv[1] + t_;           \
    acc = A[0] * Bv[0] + t_;          \
  } while (0)

// ---------------------------- main kernel ----------------------------------

__global__ __launch_bounds__(256)
__attribute__((amdgpu_waves_per_eu(2, 4)))
void LRF_70695161692718_kernel(
    const float* __restrict__ xyz, const float* __restrict__ xyzg,
    const float* __restrict__ rl, float* __restrict__ out, int B) {
#pragma clang fp contract(off)
  int tid = blockIdx.x * blockDim.x + threadIdx.x;
  int b = tid >> 2;        // batch
  int l = tid & 3;         // einsum SIMD lane (column class c % 4 == l)
  if (b >= B) return;
  const float* Xg = xyzg + (size_t)b * 192;
  float cx = xyz[3 * b + 0], cy = xyz[3 * b + 1], cz = xyz[3 * b + 2];
  float r = rl[b];

  // Load this lane's 48 floats once into VGPRs: columns c = 4*i + l.
  float r0[16], r1[16], r2[16];
#pragma unroll
  for (int i = 0; i < 16; ++i) {
    int col = 4 * i + l;
    r0[i] = Xg[col];
    r1[i] = Xg[64 + col];
    r2[i] = Xg[128 + col];
  }

  // ---- pass 1: covariance (exact einsum chain per lane + quad hadd)
  float a00 = 0, a01 = 0, a02 = 0, a11 = 0, a12 = 0, a22 = 0;
#pragma unroll
  for (int Bk = 0; Bk < 4; ++Bk) {
    float x0[4], x1[4], x2[4];
#pragma unroll
    for (int j = 0; j < 4; ++j) {
      int i = 4 * Bk + j;
      x0[j] = cx - r0[i];
      x1[j] = cy - r1[i];
      x2[j] = cz - r2[i];
    }
    CHAIN4(a00, x0, x0);
    CHAIN4(a01, x0, x1);
    CHAIN4(a02, x0, x2);
    CHAIN4(a11, x1, x1);
    CHAIN4(a12, x1, x2);
    CHAIN4(a22, x2, x2);
  }
  a00 = qsum(a00) / 64.0f;
  a01 = qsum(a01) / 64.0f;
  a02 = qsum(a02) / 64.0f;
  a11 = qsum(a11) / 64.0f;
  a12 = qsum(a12) / 64.0f;
  a22 = qsum(a22) / 64.0f;

  float v[3];
  svd3_vlast(a00, a01, a02, a11, a12, a22, v);  // redundant across quad: free

  // ---- pass 2: center_proj counts (integer, order-free across quad)
  int npos = 0, nneg = 0;
#pragma unroll
  for (int i = 0; i < 16; ++i) {
    float x0 = cx - r0[i];
    float x1 = cy - r1[i];
    float x2 = cz - r2[i];
    float p = v[0] * x0;
    p = v[1] * x1 + p;
    p = v[2] * x2 + p;
    npos += (p > 0.001f) ? 1 : 0;
    nneg += (p < -0.001f) ? 1 : 0;
  }
  int sum_ = qsumi(npos) - qsumi(nneg);
  float sgn = (sum_ < 0) ? -1.0f : 1.0f;
  float zp0 = sgn * v[0], zp1 = sgn * v[1], zp2 = sgn * v[2];

  // ---- pass 3: vi_c (exact einsum chain per lane + quad hadd)
  float vx = 0, vy = 0, vz = 0;
#pragma unroll
  for (int Bk = 0; Bk < 4; ++Bk) {
    float w[4], q0[4], q1[4], q2[4];
#pragma unroll
    for (int j = 0; j < 4; ++j) {
      int i = 4 * Bk + j;
      float y0 = r0[i] - cx;
      float y1 = r1[i] - cy;
      float y2 = r2[i] - cz;
      float nm = zp0 * y0;
      nm = zp1 * y1 + nm;
      nm = zp2 * y2 + nm;
      q0[j] = y0 - zp0 * nm;
      q1[j] = y1 - zp1 * nm;
      q2[j] = y2 - zp2 * nm;
      float ss = y0 * y0;
      ss = ss + y1 * y1;
      ss = ss + y2 * y2;
      float xl2 = sqrtf(ss);
      float am = r - xl2;
      float alpha = am * am;
      float beta = nm * nm;
      w[j] = alpha * beta;
    }
    CHAIN4(vx, w, q0);
    CHAIN4(vy, w, q1);
    CHAIN4(vz, w, q2);
  }
  float vcx = qsum(vx);
  float vcy = qsum(vy);
  float vcz = qsum(vz);
  float ss = vcx * vcx;
  ss = ss + vcy * vcy;
  ss = ss + vcz * vcz;
  float den = sqrtf(ss) + 1e-10f;
  float xp0 = vcx / den, xp1 = vcy / den, xp2 = vcz / den;
  float yp0 = xp1 * zp2 - xp2 * zp1;
  float yp1 = xp2 * zp0 - xp0 * zp2;
  float yp2 = xp0 * zp1 - xp1 * zp0;

  // ---- pass 4: rotate and write this lane's 16 columns
  float* O = out + (size_t)b * 192;
#pragma unroll
  for (int i = 0; i < 16; ++i) {
    int col = 4 * i + l;
    float y0 = r0[i] - cx;
    float y1 = r1[i] - cy;
    float y2 = r2[i] - cz;
    float p0 = y0 / r, p1 = y1 / r, p2 = y2 / r;
    float t0 = xp0 * p0; t0 = xp1 * p1 + t0; t0 = xp2 * p2 + t0;
    float t1 = yp0 * p0; t1 = yp1 * p1 + t1; t1 = yp2 * p2 + t1;
    float t2 = zp0 * p0; t2 = zp1 * p1 + t2; t2 = zp2 * p2 + t2;
    O[col] = t0;
    O[64 + col] = t1;
    O[128 + col] = t2;
  }
}

extern "C" void kernel_launch(void* const* d_in, const int* in_sizes, int n_in,
                              void* d_out, int out_size, void* d_ws, size_t ws_size,
                              hipStream_t stream) {
  (void)n_in; (void)out_size; (void)d_ws; (void)ws_size;
  const float* xyz = (const float*)d_in[0];
  const float* xyzg = (const float*)d_in[1];
  const float* rl = (const float*)d_in[2];
  float* out = (float*)d_out;
  int B = in_sizes[2];  // r_lrf has one element per batch
  int threads = 256;
  int blocks = (B * 4 + threads - 1) / threads;
  LRF_70695161692718_kernel<<<blocks, threads, 0, stream>>>(xyz, xyzg, rl, out, B);
}